// Round 11
// baseline (98.184 us; speedup 1.0000x reference)
//
#include <hip/hip_runtime.h>

// B=32, C=16, RES=128, NA=64
// out[b,0,a,i] = bias + sum_j bilinear(y[b],...), y[b] = sum_c w[c]*x[b,c]
//
// ANGLE-MIRROR SYMMETRY: theta_{63-k} = 2pi - theta_k exactly (linspace).
// proj_{2pi-theta}(i) on Y == proj_theta(i) on the vertically flipped Y,
// with IDENTICAL per-j addresses and bilinear weights (j traversal reversed,
// which a sum doesn't care about). So each 8-B LDS element packs 4 fp16:
//   E[r][c] = (b0[r-2,c-2], b0[129-r,c-2], b1[r-2,c-2], b1[129-r,c-2])
// (guard coords; 2-px zero border). One iteration = 2x ds_read2_b64 + one
// set of addr/weight math -> FOUR outputs (2 batches x 2 mirrored angles).
// Grid: 16 bpairs x 8 agroups x 2 j-halves = 256 blocks, 147 KB LDS
// (1 block/CU), halves combined by f32 atomicAdd into memset-zeroed out.

#define B_    32
#define C_    16
#define RES   128
#define NA    64
#define SLDS  133              // row stride in 8-B elements (read2_b64 offs <= 255)
#define ROWS  132
#define NELEM (ROWS * SLDS)    // 17556 elements
#define NPADE 18432            // padded: 18432*8 B = 147456 B = 512 thr * 18 uint4
#define NPAIR 16

typedef _Float16 half2v __attribute__((ext_vector_type(2)));

// ---------------- Kernel 1: fused channel-reduce + mirror pair-pack ----------------
// grid = 16 pairs x 128 rows, 256 threads; t: u = t>>7 (batch), m = t&127 (col)
// Block q writes its row into element row q+2 (lanes 0,2) AND element row
// 129-q (lanes 1,3) as ushort stores; block 127-q writes the complementary
// lanes of the same rows -> byte-disjoint, race-free.
__global__ __launch_bounds__(256) void chanpack(const float* __restrict__ x,
                                                const float* __restrict__ w,
                                                unsigned short* __restrict__ pk16) {
    const int blk = blockIdx.x;
    const int p   = blk >> 7;          // pair
    const int q   = blk & 127;         // image row
    const int t   = threadIdx.x;
    const int u   = t >> 7;            // batch within pair
    const int m   = t & 127;           // column

    __shared__ float rowbuf[2][128];

    float wr[C_];
#pragma unroll
    for (int c = 0; c < C_; ++c) wr[c] = w[c];

    const float* xb = x + ((size_t)(2 * p + u) * C_) * (RES * RES) + q * RES + m;
    float acc = 0.f;
#pragma unroll
    for (int c = 0; c < C_; ++c) acc = fmaf(wr[c], xb[c * (RES * RES)], acc);

    rowbuf[u][m] = acc;
    __syncthreads();

    if (t < SLDS) {
        int c = t;
        unsigned short v0 = 0, v1 = 0;
        if (c >= 2 && c <= 129) {
            v0 = __builtin_bit_cast(unsigned short, (_Float16)rowbuf[0][c - 2]);
            v1 = __builtin_bit_cast(unsigned short, (_Float16)rowbuf[1][c - 2]);
        }
        size_t base = (size_t)p * NPADE * 4;                 // ushort units
        size_t e1 = base + (size_t)((q + 2)   * SLDS + c) * 4;
        size_t e2 = base + (size_t)((129 - q) * SLDS + c) * 4;
        pk16[e1 + 0] = v0;  pk16[e1 + 2] = v1;               // lanes 0,2 (direct)
        pk16[e2 + 1] = v0;  pk16[e2 + 3] = v1;               // lanes 1,3 (mirror)
    }

    // q==0 blocks zero guard rows (0,1,130,131) and the pad tail (all lanes)
    if (q == 0) {
        uint2* base = (uint2*)pk16 + (size_t)p * NPADE;
        const uint2 z = make_uint2(0u, 0u);
        for (int k = t; k < 2 * SLDS; k += 256) {
            base[k] = z;                        // rows 0,1
            base[130 * SLDS + k] = z;           // rows 130,131
        }
        for (int k = t; k < NPADE - NELEM; k += 256)
            base[NELEM + k] = z;                // pad tail
    }
}

// ---------------- Kernel 2: radon, 2 batches x 2 angles per sample ----------------
// grid = 16 bpairs x 8 agroups x 2 jhalf = 256 blocks, 512 threads
// thread t: slot = t>>7 -> angle-pair ap = slot*8 + agroup; a1 = ap, a2 = 63-ap
__global__ __launch_bounds__(512) void radon_k(const uint2* __restrict__ pk,
                                               const float* __restrict__ angles,
                                               const float* __restrict__ bias,
                                               float* __restrict__ out) {
    __shared__ uint2 lds[NPADE];   // 147456 B -> 1 block/CU
    const int bid = blockIdx.x;
    const int h   = bid & 1;              // j-half
    const int ag  = (bid >> 1) & 7;       // angle group
    const int p   = bid >> 4;             // batch pair
    const int t   = threadIdx.x;

    // ---- branch-free bulk stage: 18 uint4 per thread ----
    {
        const uint4* src = (const uint4*)(pk + (size_t)p * NPADE);
        uint4*       dst = (uint4*)lds;
#pragma unroll
        for (int k = 0; k < 18; ++k) dst[k * 512 + t] = src[k * 512 + t];
    }
    __syncthreads();

    const int ap = (t >> 7) * 8 + ag;     // wave-uniform angle pair [0,32)
    const int a1 = ap, a2 = 63 - ap;
    const int i  = t & 127;
    float th = angles[a1];
    float s, c;
    __sincosf(th, &s, &c);

    const float ci = (float)i - 63.5f;
    const float j0 = (float)(h * 64);
    const float Xb = fmaf(ci, c, fmaf(63.5f - j0, s, 65.5f));
    const float Yb = fmaf(ci, s, fmaf(j0 - 63.5f, c, 65.5f));
    const float ns = -s;

    float ab0a1 = 0.f, ab0a2 = 0.f, ab1a1 = 0.f, ab1a2 = 0.f;
#pragma unroll 8
    for (int j = 0; j < 64; ++j) {
        float jf = (float)j;
        float X  = fmaf(jf, ns, Xb);
        float Y  = fmaf(jf, c,  Yb);
        float fx = floorf(X), fy = floorf(Y);
        float wx = X - fx,    wy = Y - fy;
        float gx = fminf(fmaxf(fx, 0.f), 130.f);    // v_med3_f32
        float gy = fminf(fmaxf(fy, 0.f), 130.f);
        int addr = (int)fmaf(gy, (float)SLDS, gx);  // exact (< 2^24)
        uint2 q00 = lds[addr];                      // (b0,b0m | b1,b1m) row gy, col gx
        uint2 q01 = lds[addr + 1];                  //   — ds_read2_b64 {0,1}
        uint2 q10 = lds[addr + SLDS];
        uint2 q11 = lds[addr + SLDS + 1];           //   — ds_read2_b64 {133,134}
        float un = 1.f - wx;
        float A0 = 1.f - wy;
        float w00 = A0 * un, w01 = A0 * wx, w10 = wy * un, w11 = wy * wx;

        half2v e00a = __builtin_bit_cast(half2v, q00.x), e00b = __builtin_bit_cast(half2v, q00.y);
        half2v e01a = __builtin_bit_cast(half2v, q01.x), e01b = __builtin_bit_cast(half2v, q01.y);
        half2v e10a = __builtin_bit_cast(half2v, q10.x), e10b = __builtin_bit_cast(half2v, q10.y);
        half2v e11a = __builtin_bit_cast(half2v, q11.x), e11b = __builtin_bit_cast(half2v, q11.y);

        ab0a1 = fmaf((float)e00a.x, w00, ab0a1);    // v_fma_mix_f32
        ab0a2 = fmaf((float)e00a.y, w00, ab0a2);
        ab1a1 = fmaf((float)e00b.x, w00, ab1a1);
        ab1a2 = fmaf((float)e00b.y, w00, ab1a2);
        ab0a1 = fmaf((float)e01a.x, w01, ab0a1);
        ab0a2 = fmaf((float)e01a.y, w01, ab0a2);
        ab1a1 = fmaf((float)e01b.x, w01, ab1a1);
        ab1a2 = fmaf((float)e01b.y, w01, ab1a2);
        ab0a1 = fmaf((float)e10a.x, w10, ab0a1);
        ab0a2 = fmaf((float)e10a.y, w10, ab0a2);
        ab1a1 = fmaf((float)e10b.x, w10, ab1a1);
        ab1a2 = fmaf((float)e10b.y, w10, ab1a2);
        ab0a1 = fmaf((float)e11a.x, w11, ab0a1);
        ab0a2 = fmaf((float)e11a.y, w11, ab0a2);
        ab1a1 = fmaf((float)e11b.x, w11, ab1a1);
        ab1a2 = fmaf((float)e11b.y, w11, ab1a2);
    }

    float bv = (h == 0) ? bias[0] : 0.f;
    float* o0 = out + (size_t)(2 * p) * (NA * RES);
    float* o1 = o0 + NA * RES;
    atomicAdd(&o0[a1 * RES + i], ab0a1 + bv);
    atomicAdd(&o0[a2 * RES + i], ab0a2 + bv);
    atomicAdd(&o1[a1 * RES + i], ab1a1 + bv);
    atomicAdd(&o1[a2 * RES + i], ab1a2 + bv);
}

extern "C" void kernel_launch(void* const* d_in, const int* in_sizes, int n_in,
                              void* d_out, int out_size, void* d_ws, size_t ws_size,
                              hipStream_t stream) {
    const float* x      = (const float*)d_in[0];   // 32*16*128*128
    const float* angles = (const float*)d_in[1];   // 64
    const float* w      = (const float*)d_in[2];   // 16
    const float* bias   = (const float*)d_in[3];   // 1
    float* out = (float*)d_out;                    // 32*64*128 fp32

    unsigned short* pk16 = (unsigned short*)d_ws;  // 16*18432*8 B = 2.36 MiB

    hipMemsetAsync(out, 0, (size_t)out_size * sizeof(float), stream);  // capture-safe
    chanpack<<<dim3(NPAIR * RES), dim3(256), 0, stream>>>(x, w, pk16);
    radon_k<<<dim3(NPAIR * 8 * 2), dim3(512), 0, stream>>>((const uint2*)pk16,
                                                           angles, bias, out);
}

// Round 12
// 97.881 us; speedup vs baseline: 1.0031x; 1.0031x over previous
//
#include <hip/hip_runtime.h>

// B=32, C=16, RES=128, NA=64
// out[b,0,a,i] = bias + sum_j bilinear(y[b],...), y[b] = sum_c w[c]*x[b,c]
//
// FINAL (= Round-9, measured best 96.83 us):
// FRONT-END (fused): chanpack computes channel-reduced rows for a batch pair
// and emits the guarded packed pair-row:
//   pk(p,r,c) = (y0[r-2,c-2], y0[r-2,c-1], y1[r-2,c-2], y1[r-2,c-1]) 4xfp16,
//   2-px zero guard band -> no boundary masks/cmps in the radon inner loop.
// RADON: 2 batches/block, LDS-resident packed image (147 KB), ONE
// ds_read2_b64 per sample-pair feeding 4 x v_dot2_f32_f16; depth-2 SW
// pipeline + packed-fp16 weight math (both measured neutral but not harmful).
// Post-sweep: conflict-free strides, 4 waves/SIMD, and angle-mirror symmetry
// all measured neutral within +/-1.5% — this structure is the practical floor
// against ~80 us of fixed harness overhead.

#define B_    32
#define C_    16
#define RES   128
#define NA    64
#define SLDS  133              // row stride in 8-B elements (ds_read2_b64 offset1=133 <= 255)
#define ROWS  132
#define NELEM (ROWS * SLDS)    // 17556 elements
#define NPAD  18432            // padded: 18432*8 B = 147456 B = 512 thr * 18 uint4
#define NPAIR 16

typedef _Float16 half2v __attribute__((ext_vector_type(2)));

// ---------------- Kernel 1: fused channel-reduce + guarded pair-pack ----------------
// grid = 16 pairs x 128 rows, 256 threads; t: u = t>>7 (batch), m = t&127 (col)
__global__ __launch_bounds__(256) void chanpack(const float* __restrict__ x,
                                                const float* __restrict__ w,
                                                uint2* __restrict__ pk) {
    const int blk = blockIdx.x;
    const int p   = blk >> 7;          // pair
    const int q   = blk & 127;         // image row
    const int t   = threadIdx.x;
    const int u   = t >> 7;            // batch within pair
    const int m   = t & 127;           // column

    __shared__ float rowbuf[2][130];   // y[k] at [u][k+1]; [u][0]=[u][129]=0

    float wr[C_];
#pragma unroll
    for (int c = 0; c < C_; ++c) wr[c] = w[c];

    const float* xb = x + ((size_t)(2 * p + u) * C_) * (RES * RES) + q * RES + m;
    float acc = 0.f;
#pragma unroll
    for (int c = 0; c < C_; ++c) acc = fmaf(wr[c], xb[c * (RES * RES)], acc);

    rowbuf[u][m + 1] = acc;
    if (m == 0) { rowbuf[u][0] = 0.f; rowbuf[u][129] = 0.f; }
    __syncthreads();

    // packed row r = q+2; nonzero for c in [1..129]
    uint2* dst = pk + (size_t)p * NPAD + (q + 2) * SLDS;
    if (t < SLDS) {
        int c = t;
        uint2 v = make_uint2(0u, 0u);
        if (c >= 1 && c <= 129) {
            v.x = __builtin_bit_cast(unsigned int,
                      __builtin_amdgcn_cvt_pkrtz(rowbuf[0][c - 1], rowbuf[0][c]));
            v.y = __builtin_bit_cast(unsigned int,
                      __builtin_amdgcn_cvt_pkrtz(rowbuf[1][c - 1], rowbuf[1][c]));
        }
        dst[c] = v;
    }

    // q==0 blocks zero the guard rows (0,1,130,131) and the pad tail
    if (q == 0) {
        uint2* base = pk + (size_t)p * NPAD;
        const uint2 z = make_uint2(0u, 0u);
        for (int k = t; k < 2 * SLDS; k += 256) {
            base[k] = z;
            base[130 * SLDS + k] = z;
        }
        for (int k = t; k < NPAD - NELEM; k += 256)
            base[NELEM + k] = z;
    }
}

// ---------------- Kernel 2: radon, 2 batches per block ----------------
// grid = 16 pairs x 16 groups = 256 blocks, 512 threads
__global__ __launch_bounds__(512) void radon_k(const uint2* __restrict__ pk,
                                               const float* __restrict__ angles,
                                               const float* __restrict__ bias,
                                               float* __restrict__ out) {
    __shared__ uint2 lds[NPAD];   // 147456 B
    const int bid = blockIdx.x;
    const int p   = bid >> 4;
    const int grp = bid & 15;
    const int t   = threadIdx.x;

    // ---- branch-free bulk stage: 18 uint4 per thread, guards included ----
    {
        const uint4* src = (const uint4*)(pk + (size_t)p * NPAD);
        uint4*       dst = (uint4*)lds;
#pragma unroll
        for (int k = 0; k < 18; ++k) dst[k * 512 + t] = src[k * 512 + t];
    }
    __syncthreads();

    const int a = (t >> 7) * 16 + grp;     // wave-uniform angle
    const int i = t & 127;
    float th = angles[a];
    float s, c;
    __sincosf(th, &s, &c);

    const float ci = (float)i - 63.5f;
    const float Xb = fmaf(ci, c, fmaf(63.5f, s, 65.5f));
    const float Yb = fmaf(ci, s, fmaf(-63.5f, c, 65.5f));
    const float ns = -s;

    // packed-fp16 weight constants: uw = pk_fma(h, kM1P1, kP1Z) = (1-w, w)
    const half2v kM1P1 = half2v{(_Float16)(-1.f), (_Float16)(1.f)};
    const half2v kP1Z  = half2v{(_Float16)( 1.f), (_Float16)(0.f)};

    auto addr_of = [&](float jf) -> int {
        float X  = fmaf(jf, ns, Xb);
        float Y  = fmaf(jf, c,  Yb);
        float gx = fminf(fmaxf(floorf(X), 0.f), 130.f);
        float gy = fminf(fmaxf(floorf(Y), 0.f), 130.f);
        return (int)fmaf(gy, (float)SLDS, gx);      // exact (< 2^24)
    };

    float acc00 = 0.f, acc01 = 0.f, acc10 = 0.f, acc11 = 0.f;

    int   addr = addr_of(0.f);
    uint2 q0 = lds[addr];                   // prologue loads for j=0
    uint2 q1 = lds[addr + SLDS];

#pragma unroll 8
    for (int j = 0; j < RES; ++j) {
        float jf = (float)j;
        float X  = fmaf(jf, ns, Xb);
        float Y  = fmaf(jf, c,  Yb);
        float wx = X - floorf(X);
        float wy = Y - floorf(Y);

        // issue next iteration's loads before consuming current
        uint2 q0n, q1n;
        if (j < RES - 1) {
            int an = addr_of(jf + 1.f);
            q0n = lds[an];
            q1n = lds[an + SLDS];
        }

        half2v hwx = __builtin_bit_cast(half2v, __builtin_amdgcn_cvt_pkrtz(wx, wx));
        half2v hwy = __builtin_bit_cast(half2v, __builtin_amdgcn_cvt_pkrtz(wy, wy));
        half2v uwx = __builtin_elementwise_fma(hwx, kM1P1, kP1Z);   // (1-wx, wx)
        half2v uwy = __builtin_elementwise_fma(hwy, kM1P1, kP1Z);   // (1-wy, wy)
        half2v wa  = uwx * __builtin_shufflevector(uwy, uwy, 0, 0); // *(1-wy)
        half2v wb  = uwx * __builtin_shufflevector(uwy, uwy, 1, 1); // *wy

        acc00 = __builtin_amdgcn_fdot2(__builtin_bit_cast(half2v, q0.x), wa, acc00, false);
        acc10 = __builtin_amdgcn_fdot2(__builtin_bit_cast(half2v, q0.y), wa, acc10, false);
        acc01 = __builtin_amdgcn_fdot2(__builtin_bit_cast(half2v, q1.x), wb, acc01, false);
        acc11 = __builtin_amdgcn_fdot2(__builtin_bit_cast(half2v, q1.y), wb, acc11, false);

        q0 = q0n; q1 = q1n;
    }

    float bv = bias[0];
    out[(2 * p)     * (NA * RES) + a * RES + i] = (acc00 + acc01) + bv;
    out[(2 * p + 1) * (NA * RES) + a * RES + i] = (acc10 + acc11) + bv;
}

extern "C" void kernel_launch(void* const* d_in, const int* in_sizes, int n_in,
                              void* d_out, int out_size, void* d_ws, size_t ws_size,
                              hipStream_t stream) {
    const float* x      = (const float*)d_in[0];   // 32*16*128*128
    const float* angles = (const float*)d_in[1];   // 64
    const float* w      = (const float*)d_in[2];   // 16
    const float* bias   = (const float*)d_in[3];   // 1
    float* out = (float*)d_out;                    // 32*64*128 fp32

    uint2* pk = (uint2*)d_ws;                      // 16*18432*8 B = 2.36 MiB

    chanpack<<<dim3(NPAIR * RES), dim3(256), 0, stream>>>(x, w, pk);
    radon_k<<<dim3(NPAIR * 16), dim3(512), 0, stream>>>(pk, angles, bias, out);
}